// Round 2
// baseline (57.632 us; speedup 1.0000x reference)
//
#include <hip/hip_runtime.h>

#define MARGIN 0.5f
#define EPS    1e-6f
#define BN     8192
#define TPB    256
#define NBLK   1024
#define JV     4
// 262144 threads; 2048 column-groups of 4 j's each; 128 threads/group sweep
// i = ib + 128*k, k=0..63.  Pairs/thread = 4*64 = 256; total = 67,108,864. ✓
// i-side loads are block-uniform (broadcast); j-side loads are coalesced float4.

#define FIXSCALE 4294967296.0   // 2^32 fixed-point for deterministic atomic sum

__global__ __launch_bounds__(TPB) void pairloss_fused(
    const float* __restrict__ preds,
    const float* __restrict__ targets,
    const int*   __restrict__ pdb,
    unsigned long long* __restrict__ ws,   // ws[0]=fixed sum, ws[1]=count, ws[2]=arrival
    float* __restrict__ out)
{
    const int t  = blockIdx.x * TPB + threadIdx.x;   // 0..262143
    const int g  = t & 2047;                          // column group
    const int ib = t >> 11;                           // 0..127 (block-uniform)

    // j-side: 4 columns, coalesced 16B loads
    const float4 pj4 = ((const float4*)preds)[g];
    const float4 tj4 = ((const float4*)targets)[g];
    const int4   gj4 = ((const int4*)pdb)[g];

    const float cj[JV] = { MARGIN + pj4.x, MARGIN + pj4.y, MARGIN + pj4.z, MARGIN + pj4.w };
    const float te[JV] = { tj4.x + EPS,    tj4.y + EPS,    tj4.z + EPS,    tj4.w + EPS    };
    const int   gj[JV] = { gj4.x, gj4.y, gj4.z, gj4.w };

    float s[JV] = {0.f, 0.f, 0.f, 0.f};
    int   c[JV] = {0, 0, 0, 0};

    #pragma unroll 4
    for (int k = 0; k < 64; ++k) {
        const int i  = ib + (k << 7);     // block-uniform -> broadcast loads
        const float ti = targets[i];
        const float pi = preds[i];
        const int   gi = pdb[i];
        #pragma unroll
        for (int jv = 0; jv < JV; ++jv) {
            const bool v = (gi == gj[jv]) && (ti > te[jv]);
            const float h = fmaxf(cj[jv] - pi, 0.0f);
            s[jv] += v ? h : 0.0f;
            c[jv] += v ? 1 : 0;
        }
    }

    float sum = (s[0] + s[1]) + (s[2] + s[3]);
    int   cnt = (c[0] + c[1]) + (c[2] + c[3]);

    // 64-lane wave reduce
    #pragma unroll
    for (int off = 32; off > 0; off >>= 1) {
        sum += __shfl_down(sum, off);
        cnt += __shfl_down(cnt, off);
    }

    __shared__ float wsm[TPB / 64];
    __shared__ int   wcm[TPB / 64];
    const int lane = threadIdx.x & 63;
    const int wv   = threadIdx.x >> 6;
    if (lane == 0) { wsm[wv] = sum; wcm[wv] = cnt; }
    __syncthreads();

    if (threadIdx.x == 0) {
        float bs = 0.f; int bc = 0;
        #pragma unroll
        for (int w = 0; w < TPB / 64; ++w) { bs += wsm[w]; bc += wcm[w]; }

        // deterministic: integer atomics are associative/commutative
        const unsigned long long fx = (unsigned long long)(long long)((double)bs * FIXSCALE);
        atomicAdd(&ws[0], fx);
        atomicAdd(&ws[1], (unsigned long long)(unsigned int)bc);
        __threadfence();
        const unsigned int old = atomicAdd((unsigned int*)&ws[2], 1u);
        if (old == NBLK - 1) {            // last block finalizes
            __threadfence();
            const unsigned long long fs = atomicAdd(&ws[0], 0ull);
            const unsigned long long fc = atomicAdd(&ws[1], 0ull);
            const double S = (double)(long long)fs / FIXSCALE;
            const long long C = (long long)fc;
            out[0] = (C == 0) ? 0.0f : (float)(S / (double)C);
        }
    }
}

extern "C" void kernel_launch(void* const* d_in, const int* in_sizes, int n_in,
                              void* d_out, int out_size, void* d_ws, size_t ws_size,
                              hipStream_t stream)
{
    const float* preds   = (const float*)d_in[0];
    const float* targets = (const float*)d_in[1];
    const int*   pdb     = (const int*)d_in[2];
    float* out = (float*)d_out;
    unsigned long long* ws = (unsigned long long*)d_ws;

    hipMemsetAsync(ws, 0, 3 * sizeof(unsigned long long), stream);
    pairloss_fused<<<NBLK, TPB, 0, stream>>>(preds, targets, pdb, ws, out);
}

// Round 3
// 22.087 us; speedup vs baseline: 2.6093x; 2.6093x over previous
//
#include <hip/hip_runtime.h>

#define MARGIN 0.5f
#define EPS    1e-6f
#define BN     8192
#define TPB    1024
#define KPT    (BN / TPB)   // 8 elements per thread
#define NPDB   512

// Single-block grouped pairwise hinge loss.
// Valid pairs exist only within a pdb group (avg size 16) -> only ~131k pairs
// total. Bucketize in LDS, then sweep each element against its own group.
__global__ __launch_bounds__(TPB) void pairloss_grouped(
    const float* __restrict__ preds,
    const float* __restrict__ targets,
    const int*   __restrict__ pdb,
    float* __restrict__ out)
{
    __shared__ int   hist[NPDB];      // group counts
    __shared__ int   scanex[NPDB];    // exclusive prefix (group start)
    __shared__ int   cur[NPDB];       // scatter cursor
    __shared__ int   wtot[8];         // per-wave scan totals
    __shared__ unsigned short grp[BN];
    __shared__ float2 sorted[BN];     // (pred, target) in group-contiguous order
    __shared__ double rsum[TPB / 64];
    __shared__ int    rcnt[TPB / 64];

    const int t    = threadIdx.x;
    const int lane = t & 63;
    const int wv   = t >> 6;

    if (t < NPDB) hist[t] = 0;
    __syncthreads();

    // ---- histogram (coalesced pdb loads, LDS atomics) ----
    int myg[KPT];
    #pragma unroll
    for (int k = 0; k < KPT; ++k) {
        myg[k] = pdb[t + k * TPB];
        atomicAdd(&hist[myg[k]], 1);
    }
    __syncthreads();

    // ---- inclusive scan over 512 bins: 8 full waves shfl-scan + wave offsets ----
    int v = 0;
    if (t < NPDB) {                       // waves 0..7 fully active
        v = hist[t];
        #pragma unroll
        for (int off = 1; off < 64; off <<= 1) {
            int n = __shfl_up(v, off);
            if (lane >= off) v += n;
        }
        if (lane == 63) wtot[wv] = v;
    }
    __syncthreads();
    if (t < NPDB) {
        int add = 0;
        for (int w = 0; w < wv; ++w) add += wtot[w];
        const int excl = (v + add) - hist[t];
        scanex[t] = excl;
        cur[t]    = excl;
    }
    __syncthreads();

    // ---- scatter into group-contiguous order ----
    #pragma unroll
    for (int k = 0; k < KPT; ++k) {
        const int i = t + k * TPB;
        const int g = myg[k];
        const int pos = atomicAdd(&cur[g], 1);
        sorted[pos] = make_float2(preds[i], targets[i]);
        grp[pos]    = (unsigned short)g;
    }
    __syncthreads();

    // ---- pair sweep: each position vs its own group only ----
    float sum = 0.0f;
    int   cnt = 0;
    #pragma unroll
    for (int k = 0; k < KPT; ++k) {
        const int s = t + k * TPB;        // adjacent lanes -> adjacent positions
        const float2 pt = sorted[s];      //   -> same group, uniform bounds,
        const int g  = grp[s];            //      broadcast LDS reads of sorted[j]
        const int st = scanex[g];
        const int en = st + hist[g];
        const float pi = pt.x;
        const float ti = pt.y;
        for (int j = st; j < en; ++j) {   // j == s can't pass (ti > ti+eps false)
            const float2 q = sorted[j];
            const bool ok = ti > (q.y + EPS);
            const float h = fmaxf((MARGIN - pi) + q.x, 0.0f);
            sum += ok ? h : 0.0f;
            cnt += ok ? 1 : 0;
        }
    }

    // ---- block reduce (fixed order -> deterministic) ----
    double ds = (double)sum;
    #pragma unroll
    for (int off = 32; off > 0; off >>= 1) {
        ds  += __shfl_down(ds, off);
        cnt += __shfl_down(cnt, off);
    }
    if (lane == 0) { rsum[wv] = ds; rcnt[wv] = cnt; }
    __syncthreads();
    if (t == 0) {
        double S = 0.0; int C = 0;
        #pragma unroll
        for (int w = 0; w < TPB / 64; ++w) { S += rsum[w]; C += rcnt[w]; }
        out[0] = (C == 0) ? 0.0f : (float)(S / (double)C);
    }
}

extern "C" void kernel_launch(void* const* d_in, const int* in_sizes, int n_in,
                              void* d_out, int out_size, void* d_ws, size_t ws_size,
                              hipStream_t stream)
{
    const float* preds   = (const float*)d_in[0];
    const float* targets = (const float*)d_in[1];
    const int*   pdb     = (const int*)d_in[2];
    float* out = (float*)d_out;

    pairloss_grouped<<<1, TPB, 0, stream>>>(preds, targets, pdb, out);
}